// Round 15
// baseline (176.574 us; speedup 1.0000x reference)
//
#include <hip/hip_runtime.h>

// ---------- types / helpers ----------
typedef __attribute__((ext_vector_type(8))) __bf16 bf16x8;
typedef __attribute__((ext_vector_type(8))) ushort u16x8;
typedef __attribute__((ext_vector_type(4))) float f32x4;
typedef __attribute__((ext_vector_type(16))) float f32x16;

#define MFMA16(a, b, c) __builtin_amdgcn_mfma_f32_16x16x32_bf16(a, b, c, 0, 0, 0)
#define MFMA32(a, b, c) __builtin_amdgcn_mfma_f32_32x32x16_bf16(a, b, c, 0, 0, 0)

__device__ __forceinline__ ushort f2bf(float f) {
    union { float f; unsigned u; } v; v.f = f;
    unsigned r = v.u + 0x7FFFu + ((v.u >> 16) & 1u);
    return (ushort)(r >> 16);
}
__device__ __forceinline__ float bf2f(ushort b) {
    union { unsigned u; float f; } v; v.u = ((unsigned)b) << 16; return v.f;
}
__device__ __forceinline__ int cvtpk(float lo, float hi) {
    int r; asm("v_cvt_pk_bf16_f32 %0, %1, %2" : "=v"(r) : "v"(lo), "v"(hi)); return r;
}
__device__ __forceinline__ float fexp2(float x) {
    float r; asm("v_exp_f32 %0, %1" : "=v"(r) : "v"(x)); return r;
}
__device__ __forceinline__ void gload_lds16(const void* g, void* l) {
    __builtin_amdgcn_global_load_lds((const __attribute__((address_space(1))) void*)g,
                                     (__attribute__((address_space(3))) void*)l, 16, 0, 0);
}

// swizzle for [*,64]-elem bf16 rows: 16B group g of row at g^(row&7)
__device__ __forceinline__ int swz8(int row, int g) {
    return row * 64 + (((g) ^ (row & 7)) << 3);
}
// swizzle for [*,128]-elem bf16 rows
__device__ __forceinline__ int swz16(int row, int g) {
    return row * 128 + (((g) ^ (row & 15)) << 3);
}

// stage a 64x64 bf16 tile (global row stride rs) into linear LDS with pre-swizzled SOURCE
__device__ __forceinline__ void stage64(const ushort* __restrict__ g, int rs,
                                        char* lds, int tid) {
    const int r = tid >> 3;
    const int c8 = ((tid & 7) ^ (r & 7)) << 3;
    const int wid = tid >> 6;
    gload_lds16(g + (size_t)r * rs + c8, lds + wid * 1024);
    gload_lds16(g + (size_t)(r + 32) * rs + c8, lds + 4096 + wid * 1024);
}

// stage a 64x128 bf16 tile (rows=d, global row stride 2048) with 16-group source swizzle
__device__ __forceinline__ void stageV128(const ushort* __restrict__ g, char* lds, int tid) {
    const int w = tid >> 6, l = tid & 63;
    const int g16 = l & 15;
#pragma unroll
    for (int j = 0; j < 4; ++j) {
        const int r = w * 16 + j * 4 + (l >> 4);
        gload_lds16(g + (size_t)r * 2048 + ((g16 ^ (r & 15)) << 3), lds + w * 4096 + j * 1024);
    }
}

// ---------- merged fp32->bf16 convert (5 tensors) + RoPE tables, one launch ----------
__global__ void cvt_all(const float* __restrict__ x,  const float* __restrict__ wq,
                        const float* __restrict__ wk, const float* __restrict__ wv,
                        const float* __restrict__ wo, ushort* __restrict__ xb,
                        ushort* __restrict__ wcat, ushort* __restrict__ wob,
                        float* __restrict__ cosT, float* __restrict__ sinT) {
    int i = blockIdx.x * 256 + threadIdx.x;
    if (i >= 4718592) {
        int id = i - 4718592;
        if (id < 65536) {
            int fi = id >> 11, l = id & 2047;
            float freq = __expf(-(float)fi * (9.210340371976184f / 32.0f));
            float ph = (float)l * freq;
            cosT[id] = cosf(ph);
            sinT[id] = sinf(ph);
        }
        return;
    }
    const float* src; ushort* dst; int off;
    if (i < 2097152)      { src = x;  dst = xb;             off = i; }
    else if (i < 3145728) { src = wq; dst = wcat;           off = i - 2097152; }
    else if (i < 3407872) { src = wk; dst = wcat + 4194304; off = i - 3145728; }
    else if (i < 3670016) { src = wv; dst = wcat + 5242880; off = i - 3407872; }
    else                  { src = wo; dst = wob;            off = i - 3670016; }
    float4 v = ((const float4*)src)[off];
    ushort4 o;
    o.x = f2bf(v.x); o.y = f2bf(v.y); o.z = f2bf(v.z); o.w = f2bf(v.w);
    ((ushort4*)dst)[off] = o;
}

// ---------- QKV GEMM: 256x256 BK=64, 2-phase/tile, reads-before-barrier, counted vmcnt ----
// PROLOGUE FIX (r13 race): tile-0 staged loads must land before the t=0 pre-barrier ds_reads
// -> vmcnt(0)+barrier after prologue. Steady-state audit: t=0 p0 enters 0 outstanding;
// stgB(1)=4, vmcnt(4) noop; p1: +4 A loads =8, vmcnt(2) drains B(1)+A(1)L0 leaving A(1)L1;
// t>=1 p0 enters with 2 outstanding (A(t)L1, read in p1 after p0's vmcnt(4)+barrier). 
__global__ __launch_bounds__(512, 2) void gemmQKV2p(const ushort* __restrict__ A,
                                                    const ushort* __restrict__ B,
                                                    ushort* __restrict__ qkv,
                                                    ushort* __restrict__ vt,
                                                    const float* __restrict__ cosT,
                                                    const float* __restrict__ sinT,
                                                    int K, int gx) {
    extern __shared__ __align__(16) ushort sm[];
    ushort* sA = sm;              // 2 bufs x 16384 elems
    ushort* sB = sm + 32768;      // 2 bufs x 16384 elems
    const int tid = threadIdx.x, lane = tid & 63, wid = tid >> 6;
    const int wr = wid >> 2, wc = wid & 3;           // 2(M) x 4(N)
    const int lr = lane & 15, lg = lane >> 4;
    const int nwg = gridDim.x, bid = blockIdx.x;
    const int swz = (bid & 7) * (nwg >> 3) + (bid >> 3);
    const int m0 = (swz / gx) * 256, n0 = (swz % gx) * 256;
    const int NT = K >> 6;
    const int sr = tid >> 3;
    const int sc8 = ((tid & 7) ^ (sr & 7)) << 3;
    const ushort* gAt = A + (size_t)(m0 + sr) * K + sc8;
    const ushort* gBt = B + (size_t)(n0 + sr) * K + sc8;

    auto stgB = [&](int t, int buf) {                // all 256 B rows (4 loads)
        const ushort* g = gBt + t * 64;
        char* ld = (char*)(sB + buf * 16384) + wid * 1024;
#pragma unroll
        for (int s = 0; s < 4; ++s)
            gload_lds16(g + (size_t)(s * 64) * K, ld + s * 8192);
    };
    auto stgA_L0 = [&](int t, int buf) {             // rows 0-63 & 128-191
        const ushort* g = gAt + t * 64;
        char* ld = (char*)(sA + buf * 16384) + wid * 1024;
        gload_lds16(g, ld);
        gload_lds16(g + (size_t)128 * K, ld + 2 * 8192);
    };
    auto stgA_L1 = [&](int t, int buf) {             // rows 64-127 & 192-255
        const ushort* g = gAt + t * 64;
        char* ld = (char*)(sA + buf * 16384) + wid * 1024;
        gload_lds16(g + (size_t)64 * K, ld + 8192);
        gload_lds16(g + (size_t)192 * K, ld + 3 * 8192);
    };

    f32x4 acc[8][4] = {};
    stgB(0, 0); stgA_L0(0, 0); stgA_L1(0, 0);        // tile 0 (8 loads)
    asm volatile("s_waitcnt vmcnt(0)" ::: "memory"); // PROLOGUE DRAIN (race fix)
    __builtin_amdgcn_s_barrier();

    for (int t = 0; t < NT; ++t) {
        const int cur = t & 1;
        const ushort* Ac = sA + cur * 16384 + wr * 8192;
        const ushort* Bc = sB + cur * 16384 + (wc >> 1) * 8192;
        const int brow = (wc & 1) * 64;
        // ---- p0: frags (B all + A rows 0-63 of half), stage B(t+1), vmcnt(4), barrier ----
        bf16x8 bfr[4][2], a01[4][2];
#pragma unroll
        for (int nf = 0; nf < 4; ++nf)
#pragma unroll
            for (int kk = 0; kk < 2; ++kk)
                bfr[nf][kk] = *(const bf16x8*)&Bc[swz8(brow + nf * 16 + lr, kk * 4 + lg)];
#pragma unroll
        for (int mf = 0; mf < 4; ++mf)
#pragma unroll
            for (int kk = 0; kk < 2; ++kk)
                a01[mf][kk] = *(const bf16x8*)&Ac[swz8(mf * 16 + lr, kk * 4 + lg)];
        if (t + 1 < NT) {
            stgB(t + 1, cur ^ 1);
            asm volatile("s_waitcnt vmcnt(4)" ::: "memory");
        } else {
            asm volatile("s_waitcnt vmcnt(0)" ::: "memory");
        }
        __builtin_amdgcn_s_barrier();
        asm volatile("s_waitcnt lgkmcnt(0)" ::: "memory");
        __builtin_amdgcn_sched_barrier(0);
        __builtin_amdgcn_s_setprio(1);
#pragma unroll
        for (int mf = 0; mf < 4; ++mf)
#pragma unroll
            for (int nf = 0; nf < 4; ++nf)
#pragma unroll
                for (int kk = 0; kk < 2; ++kk)
                    acc[mf][nf] = MFMA16(a01[mf][kk], bfr[nf][kk], acc[mf][nf]);
        __builtin_amdgcn_s_setprio(0);
        // ---- p1: frags (A rows 64-127 of half), stage A(t+1), vmcnt(2), barrier ----
        bf16x8 a23[4][2];
#pragma unroll
        for (int mf = 0; mf < 4; ++mf)
#pragma unroll
            for (int kk = 0; kk < 2; ++kk)
                a23[mf][kk] = *(const bf16x8*)&Ac[swz8(64 + mf * 16 + lr, kk * 4 + lg)];
        if (t + 1 < NT) {
            stgA_L0(t + 1, cur ^ 1);
            stgA_L1(t + 1, cur ^ 1);
            asm volatile("s_waitcnt vmcnt(2)" ::: "memory");
        } else {
            asm volatile("s_waitcnt vmcnt(0)" ::: "memory");
        }
        __builtin_amdgcn_s_barrier();
        asm volatile("s_waitcnt lgkmcnt(0)" ::: "memory");
        __builtin_amdgcn_sched_barrier(0);
        __builtin_amdgcn_s_setprio(1);
#pragma unroll
        for (int mf = 0; mf < 4; ++mf)
#pragma unroll
            for (int nf = 0; nf < 4; ++nf)
#pragma unroll
                for (int kk = 0; kk < 2; ++kk)
                    acc[mf + 4][nf] = MFMA16(a23[mf][kk], bfr[nf][kk], acc[mf + 4][nf]);
        __builtin_amdgcn_s_setprio(0);
    }

    // epilogue: RoPE on Q (scaled)/K -> qkv; V transpose-scatter -> vt
    const int r0 = m0 + wr * 128 + lg * 4;
    const int c0 = n0 + wc * 64 + lr;
    const int wavecol = n0 + wc * 64;
    if (wavecol >= 2560) {
        const int kh = (wavecol - 2560) >> 6;
        const int b = m0 >> 11;
        const int l0 = r0 & 2047;
#pragma unroll
        for (int ni = 0; ni < 4; ++ni) {
            const int d = lr + ni * 16;
            ushort* vrow = vt + (size_t)((b * 8 + kh) * 64 + d) * 2048 + l0;
#pragma unroll
            for (int mi = 0; mi < 8; ++mi) {
                ushort4 o;
                o.x = f2bf(acc[mi][ni][0]); o.y = f2bf(acc[mi][ni][1]);
                o.z = f2bf(acc[mi][ni][2]); o.w = f2bf(acc[mi][ni][3]);
                *(ushort4*)(vrow + mi * 16) = o;
            }
        }
    } else {
        const float scale = (wavecol < 2048) ? 0.18033688f : 1.0f;
        const int l0 = r0 & 2047;
#pragma unroll
        for (int ni = 0; ni < 2; ++ni) {
            const int i = ni * 16 + lr;
            const float* cp = cosT + i * 2048 + l0;
            const float* sp = sinT + i * 2048 + l0;
#pragma unroll
            for (int mi = 0; mi < 8; ++mi) {
                float4 cv = *(const float4*)(cp + mi * 16);
                float4 sv = *(const float4*)(sp + mi * 16);
#pragma unroll
                for (int r = 0; r < 4; ++r) {
                    float lo = acc[mi][ni][r], hi = acc[mi][ni + 2][r];
                    float c = ((const float*)&cv)[r], s = ((const float*)&sv)[r];
                    size_t row = (size_t)(r0 + mi * 16 + r) * 3072;
                    qkv[row + c0 + ni * 16]      = f2bf((c * lo - s * hi) * scale);
                    qkv[row + c0 + ni * 16 + 32] = f2bf((c * hi + s * lo) * scale);
                }
            }
        }
    }
}

// ---------- o-proj GEMM: 256x128 BK=64, same 2-phase skeleton, waves 2Mx4N, f32 out ----------
__global__ __launch_bounds__(512, 2) void gemmO2p(const ushort* __restrict__ A,
                                                  const ushort* __restrict__ B,
                                                  float* __restrict__ C,
                                                  int N, int K, int gx) {
    extern __shared__ __align__(16) ushort sm[];
    ushort* sA = sm;              // 2 x 16384 elems
    ushort* sB = sm + 32768;      // 2 x 8192 elems
    const int tid = threadIdx.x, lane = tid & 63, wid = tid >> 6;
    const int wr = wid >> 2, wc = wid & 3;           // 2(M) x 4(N); per-wave 128x32
    const int lr = lane & 15, lg = lane >> 4;
    const int nwg = gridDim.x, bid = blockIdx.x;
    const int swz = (bid & 7) * (nwg >> 3) + (bid >> 3);
    const int m0 = (swz / gx) * 256, n0 = (swz % gx) * 128;
    const int NT = K >> 6;
    const int sr = tid >> 3;
    const int sc8 = ((tid & 7) ^ (sr & 7)) << 3;
    const ushort* gAt = A + (size_t)(m0 + sr) * K + sc8;
    const ushort* gBt = B + (size_t)(n0 + sr) * K + sc8;

    auto stgB = [&](int t, int buf) {                // 128 B rows (2 loads)
        const ushort* g = gBt + t * 64;
        char* ld = (char*)(sB + buf * 8192) + wid * 1024;
        gload_lds16(g, ld);
        gload_lds16(g + (size_t)64 * K, ld + 8192);
    };
    auto stgA_L0 = [&](int t, int buf) {
        const ushort* g = gAt + t * 64;
        char* ld = (char*)(sA + buf * 16384) + wid * 1024;
        gload_lds16(g, ld);
        gload_lds16(g + (size_t)128 * K, ld + 2 * 8192);
    };
    auto stgA_L1 = [&](int t, int buf) {
        const ushort* g = gAt + t * 64;
        char* ld = (char*)(sA + buf * 16384) + wid * 1024;
        gload_lds16(g + (size_t)64 * K, ld + 8192);
        gload_lds16(g + (size_t)192 * K, ld + 3 * 8192);
    };

    f32x4 acc[8][2] = {};
    stgB(0, 0); stgA_L0(0, 0); stgA_L1(0, 0);        // tile 0 (6 loads)
    asm volatile("s_waitcnt vmcnt(0)" ::: "memory"); // PROLOGUE DRAIN (race fix)
    __builtin_amdgcn_s_barrier();

    for (int t = 0; t < NT; ++t) {
        const int cur = t & 1;
        const ushort* Ac = sA + cur * 16384 + wr * 8192;
        const ushort* Bc = sB + cur * 8192;
        const int brow = wc * 32;
        bf16x8 bfr[2][2], a01[4][2];
#pragma unroll
        for (int nf = 0; nf < 2; ++nf)
#pragma unroll
            for (int kk = 0; kk < 2; ++kk)
                bfr[nf][kk] = *(const bf16x8*)&Bc[swz8(brow + nf * 16 + lr, kk * 4 + lg)];
#pragma unroll
        for (int mf = 0; mf < 4; ++mf)
#pragma unroll
            for (int kk = 0; kk < 2; ++kk)
                a01[mf][kk] = *(const bf16x8*)&Ac[swz8(mf * 16 + lr, kk * 4 + lg)];
        if (t + 1 < NT) {
            stgB(t + 1, cur ^ 1);
            asm volatile("s_waitcnt vmcnt(2)" ::: "memory");
        } else {
            asm volatile("s_waitcnt vmcnt(0)" ::: "memory");
        }
        __builtin_amdgcn_s_barrier();
        asm volatile("s_waitcnt lgkmcnt(0)" ::: "memory");
        __builtin_amdgcn_sched_barrier(0);
        __builtin_amdgcn_s_setprio(1);
#pragma unroll
        for (int mf = 0; mf < 4; ++mf)
#pragma unroll
            for (int nf = 0; nf < 2; ++nf)
#pragma unroll
                for (int kk = 0; kk < 2; ++kk)
                    acc[mf][nf] = MFMA16(a01[mf][kk], bfr[nf][kk], acc[mf][nf]);
        __builtin_amdgcn_s_setprio(0);
        bf16x8 a23[4][2];
#pragma unroll
        for (int mf = 0; mf < 4; ++mf)
#pragma unroll
            for (int kk = 0; kk < 2; ++kk)
                a23[mf][kk] = *(const bf16x8*)&Ac[swz8(64 + mf * 16 + lr, kk * 4 + lg)];
        if (t + 1 < NT) {
            stgA_L0(t + 1, cur ^ 1);
            stgA_L1(t + 1, cur ^ 1);
            asm volatile("s_waitcnt vmcnt(2)" ::: "memory");
        } else {
            asm volatile("s_waitcnt vmcnt(0)" ::: "memory");
        }
        __builtin_amdgcn_s_barrier();
        asm volatile("s_waitcnt lgkmcnt(0)" ::: "memory");
        __builtin_amdgcn_sched_barrier(0);
        __builtin_amdgcn_s_setprio(1);
#pragma unroll
        for (int mf = 0; mf < 4; ++mf)
#pragma unroll
            for (int nf = 0; nf < 2; ++nf)
#pragma unroll
                for (int kk = 0; kk < 2; ++kk)
                    acc[mf + 4][nf] = MFMA16(a23[mf][kk], bfr[nf][kk], acc[mf + 4][nf]);
        __builtin_amdgcn_s_setprio(0);
    }

    const int r0 = m0 + wr * 128 + lg * 4;
    const int c0 = n0 + wc * 32 + lr;
#pragma unroll
    for (int mi = 0; mi < 8; ++mi)
#pragma unroll
        for (int ni = 0; ni < 2; ++ni)
#pragma unroll
            for (int r = 0; r < 4; ++r)
                C[(size_t)(r0 + mi * 16 + r) * N + c0 + ni * 16] = acc[mi][ni][r];
}

// ---------- flash attention: KVBLK=128, swapped QK^T, static-normalization softmax ----------
__global__ __launch_bounds__(256, 2) void attn_k(const ushort* __restrict__ qkv,
                                                 const ushort* __restrict__ vt,
                                                 ushort* __restrict__ attn) {
    extern __shared__ __align__(16) ushort smem[];
    const int tid = threadIdx.x, lane = tid & 63, wid = tid >> 6;
    const int hl = lane >> 5, lq = lane & 31;
    const int p = blockIdx.x;
    const int head = blockIdx.y, b = blockIdx.z;
    const int kh = head >> 2;

    const ushort* Kg = qkv + (size_t)(b * 2048) * 3072 + 2048 + kh * 64;
    const ushort* Vg = vt + (size_t)((b * 8 + kh) * 64) * 2048;

    for (int ph = 0; ph < 2; ++ph) {
        const int qt = ph ? p : 15 - p;
        const int qb = qt << 7;
        const int qw0 = qb + wid * 32;
        const int q_lane = qw0 + lq;
        const int nt = qt + 1;

        bf16x8 qf[4];
        {
            const ushort* qp = qkv + (size_t)(b * 2048 + qw0 + lq) * 3072 + head * 64 + hl * 8;
#pragma unroll
            for (int j = 0; j < 4; ++j) qf[j] = *(const bf16x8*)(qp + j * 16);
        }
        f32x16 o0 = {}, o1 = {};
        float lsum = 0.f;

        stage64(Kg, 3072, (char*)smem, tid);
        stage64(Kg + (size_t)64 * 3072, 3072, (char*)smem + 8192, tid);
        stageV128(Vg, (char*)(smem + 16384), tid);

        for (int it = 0; it < nt; ++it) {
            const int c = it & 1;
            const int kv0 = it << 7;
            const ushort* Kc = smem + c * 8192;
            const ushort* Vc = smem + 16384 + c * 8192;
            if (it + 1 < nt) {
                const int kv1 = kv0 + 128;
                char* kd = (char*)smem + (c ^ 1) * 16384;
                char* vd = (char*)(smem + 16384) + (c ^ 1) * 16384;
                stage64(Kg + (size_t)kv1 * 3072, 3072, kd, tid);
                stage64(Kg + (size_t)(kv1 + 64) * 3072, 3072, kd + 8192, tid);
                stageV128(Vg + kv1, vd, tid);
                asm volatile("s_waitcnt vmcnt(8)" ::: "memory");
            } else {
                asm volatile("s_waitcnt vmcnt(0)" ::: "memory");
            }
            __builtin_amdgcn_s_barrier();

            f32x16 s0 = {}, s1 = {}, s2 = {}, s3 = {};
            __builtin_amdgcn_s_setprio(1);
#pragma unroll
            for (int j = 0; j < 4; ++j) {
                bf16x8 k0 = *(const bf16x8*)&Kc[swz8(lq, j * 2 + hl)];
                bf16x8 k1 = *(const bf16x8*)&Kc[swz8(32 + lq, j * 2 + hl)];
                bf16x8 k2 = *(const bf16x8*)&Kc[swz8(64 + lq, j * 2 + hl)];
                bf16x8 k3 = *(const bf16x8*)&Kc[swz8(96 + lq, j * 2 + hl)];
                s0 = MFMA32(k0, qf[j], s0);
                s1 = MFMA32(k1, qf[j], s1);
                s2 = MFMA32(k2, qf[j], s2);
                s3 = MFMA32(k3, qf[j], s3);
            }
            __builtin_amdgcn_s_setprio(0);

            if (it == qt) {
#pragma unroll
                for (int i = 0; i < 16; ++i) {
                    int r = (i & 3) + ((i >> 2) << 3) + (hl << 2) + kv0;
                    if (r > q_lane)      s0[i] = -1e30f;
                    if (r + 32 > q_lane) s1[i] = -1e30f;
                    if (r + 64 > q_lane) s2[i] = -1e30f;
                    if (r + 96 > q_lane) s3[i] = -1e30f;
                }
            }
#pragma unroll
            for (int i = 0; i < 16; ++i) s0[i] = fexp2(s0[i]);
#pragma unroll
            for (int i = 0; i < 16; ++i) s1[i] = fexp2(s1[i]);
#pragma unroll
            for (int i = 0; i < 16; ++i) s2[i] = fexp2(s2[i]);
#pragma unroll
            for (int i = 0; i < 16; ++i) s3[i] = fexp2(s3[i]);
            f32x16 ts = (s0 + s1) + (s2 + s3);
            float u0 = ts[0] + ts[1], u1 = ts[2] + ts[3], u2 = ts[4] + ts[5], u3 = ts[6] + ts[7];
            float u4 = ts[8] + ts[9], u5 = ts[10] + ts[11], u6 = ts[12] + ts[13], u7 = ts[14] + ts[15];
            float rs = ((u0 + u1) + (u2 + u3)) + ((u4 + u5) + (u6 + u7));
            {
                auto sw = __builtin_amdgcn_permlane32_swap(__float_as_int(rs), __float_as_int(rs), 0, 0);
                rs = __int_as_float(sw[0]) + __int_as_float(sw[1]);
            }
            lsum += rs;

            bf16x8 pf[8];
#define PFB(cc, q0, q1, q2, q3, q4, q5, q6, q7)                                   \
            {                                                                      \
                int pk01 = cvtpk(q0, q1), pk23 = cvtpk(q2, q3);                    \
                int pk45 = cvtpk(q4, q5), pk67 = cvtpk(q6, q7);                    \
                auto sA = __builtin_amdgcn_permlane32_swap(pk01, pk45, 0, 0);      \
                auto sB = __builtin_amdgcn_permlane32_swap(pk23, pk67, 0, 0);      \
                union { int w[4]; bf16x8 v; } u;                                   \
                u.w[0] = sA[0]; u.w[1] = sB[0]; u.w[2] = sA[1]; u.w[3] = sB[1];    \
                pf[cc] = u.v;                                                      \
            }
            PFB(0, s0[0], s0[1], s0[2], s0[3], s0[4], s0[5], s0[6], s0[7])
            PFB(1, s0[8], s0[9], s0[10], s0[11], s0[12], s0[13], s0[14], s0[15])
            PFB(2, s1[0], s1[1], s1[2], s1[3], s1[4], s1[5], s1[6], s1[7])
            PFB(3, s1[8], s1[9], s1[10], s1[11], s1[12], s1[13], s1[14], s1[15])
            PFB(4, s2[0], s2[1], s2[2], s2[3], s2[4], s2[5], s2[6], s2[7])
            PFB(5, s2[8], s2[9], s2[10], s2[11], s2[12], s2[13], s2[14], s2[15])
            PFB(6, s3[0], s3[1], s3[2], s3[3], s3[4], s3[5], s3[6], s3[7])
            PFB(7, s3[8], s3[9], s3[10], s3[11], s3[12], s3[13], s3[14], s3[15])
#undef PFB
            __builtin_amdgcn_s_setprio(1);
#pragma unroll
            for (int cc = 0; cc < 8; ++cc) {
                bf16x8 v0 = *(const bf16x8*)&Vc[swz16(lq, cc * 2 + hl)];
                bf16x8 v1 = *(const bf16x8*)&Vc[swz16(32 + lq, cc * 2 + hl)];
                o0 = MFMA32(v0, pf[cc], o0);
                o1 = MFMA32(v1, pf[cc], o1);
            }
            __builtin_amdgcn_s_setprio(0);
            __builtin_amdgcn_s_barrier();
        }

        __syncthreads();
        ushort* sc = (ushort*)((char*)smem + wid * 4096);
        float inv = 1.0f / lsum;
#pragma unroll
        for (int i = 0; i < 16; i += 2) {
            int d0 = (i & 3) + ((i >> 2) << 3) + (hl << 2);
            int g0 = d0 >> 3, g1 = (d0 + 32) >> 3;
            *(int*)&sc[lq * 64 + ((g0 ^ (lq & 7)) << 3) + (d0 & 7)] = cvtpk(o0[i] * inv, o0[i + 1] * inv);
            *(int*)&sc[lq * 64 + ((g1 ^ (lq & 7)) << 3) + (d0 & 7)] = cvtpk(o1[i] * inv, o1[i + 1] * inv);
        }
        __syncthreads();
        {
            const int q = lane >> 1, db = (lane & 1) << 5;
            const size_t orow = (size_t)(b * 2048 + qb + wid * 32 + q);
#pragma unroll
            for (int j = 0; j < 4; ++j) {
                int g = (db >> 3) + j;
                u16x8 v = *(const u16x8*)&sc[q * 64 + ((g ^ (q & 7)) << 3)];
                *(u16x8*)(attn + orow * 2048 + head * 64 + g * 8) = v;
            }
        }
        __syncthreads();
    }
}

// ---------- launch ----------
extern "C" void kernel_launch(void* const* d_in, const int* in_sizes, int n_in,
                              void* d_out, int out_size, void* d_ws, size_t ws_size,
                              hipStream_t stream) {
    const float* x  = (const float*)d_in[0];
    const float* wq = (const float*)d_in[1];
    const float* wk = (const float*)d_in[2];
    const float* wv = (const float*)d_in[3];
    const float* wo = (const float*)d_in[4];
    float* out = (float*)d_out;
    char* ws = (char*)d_ws;

    ushort* xb   = (ushort*)(ws);                 // 16 MB
    ushort* wcat = (ushort*)(ws + 16777216);      // 12 MB
    ushort* wob  = (ushort*)(ws + 29360128);      // 8 MB
    ushort* qkv  = (ushort*)(ws + 37748736);      // 24 MB
    ushort* vt   = (ushort*)(ws + 62914560);      // 4 MB
    ushort* attn = (ushort*)(ws + 67108864);      // 16 MB
    float*  cosT = (float*)(ws + 83886080);       // [32][2048] f32
    float*  sinT = (float*)(ws + 84148224);

    (void)hipFuncSetAttribute((const void*)gemmQKV2p,
                              hipFuncAttributeMaxDynamicSharedMemorySize, 131072);
    (void)hipFuncSetAttribute((const void*)gemmO2p,
                              hipFuncAttributeMaxDynamicSharedMemorySize, 98304);
    (void)hipFuncSetAttribute((const void*)attn_k,
                              hipFuncAttributeMaxDynamicSharedMemorySize, 65536);

    // fp32->bf16 conversions + rope tables, one launch
    cvt_all<<<18688, 256, 0, stream>>>(x, wq, wk, wv, wo, xb, wcat, wob, cosT, sinT);
    // QKV projection + fused RoPE + V-transpose (192 blocks, 2-phase pipelined)
    gemmQKV2p<<<192, 512, 131072, stream>>>(xb, wcat, qkv, vt, cosT, sinT, 2048, 12);
    // flash attention (512 blocks, causal-paired, KVBLK=128, static softmax)
    attn_k<<<dim3(8, 32, 2), 256, 65536, stream>>>(qkv, vt, attn);
    // output projection -> fp32 d_out (256 blocks full chip, 2-phase pipelined)
    gemmO2p<<<256, 512, 98304, stream>>>(attn, wob, out, 2048, 2048, 16);
}

// Round 16
// 166.645 us; speedup vs baseline: 1.0596x; 1.0596x over previous
//
#include <hip/hip_runtime.h>

// ---------- types / helpers ----------
typedef __attribute__((ext_vector_type(8))) __bf16 bf16x8;
typedef __attribute__((ext_vector_type(8))) ushort u16x8;
typedef __attribute__((ext_vector_type(4))) float f32x4;
typedef __attribute__((ext_vector_type(16))) float f32x16;

#define MFMA16(a, b, c) __builtin_amdgcn_mfma_f32_16x16x32_bf16(a, b, c, 0, 0, 0)
#define MFMA32(a, b, c) __builtin_amdgcn_mfma_f32_32x32x16_bf16(a, b, c, 0, 0, 0)

__device__ __forceinline__ ushort f2bf(float f) {
    union { float f; unsigned u; } v; v.f = f;
    unsigned r = v.u + 0x7FFFu + ((v.u >> 16) & 1u);
    return (ushort)(r >> 16);
}
__device__ __forceinline__ float bf2f(ushort b) {
    union { unsigned u; float f; } v; v.u = ((unsigned)b) << 16; return v.f;
}
__device__ __forceinline__ int cvtpk(float lo, float hi) {
    int r; asm("v_cvt_pk_bf16_f32 %0, %1, %2" : "=v"(r) : "v"(lo), "v"(hi)); return r;
}
__device__ __forceinline__ float fexp2(float x) {   // raw v_exp_f32, no libm wrapper
    float r; asm("v_exp_f32 %0, %1" : "=v"(r) : "v"(x)); return r;
}
__device__ __forceinline__ void gload_lds16(const void* g, void* l) {
    __builtin_amdgcn_global_load_lds((const __attribute__((address_space(1))) void*)g,
                                     (__attribute__((address_space(3))) void*)l, 16, 0, 0);
}

// swizzle for [*,64]-elem bf16 rows: 16B group g of row at g^(row&7)
__device__ __forceinline__ int swz8(int row, int g) {
    return row * 64 + (((g) ^ (row & 7)) << 3);
}
// swizzle for [*,128]-elem bf16 rows: 16B group g (0..15) of row at g^(row&15)
__device__ __forceinline__ int swz16(int row, int g) {
    return row * 128 + (((g) ^ (row & 15)) << 3);
}

// stage a 64x64 bf16 tile (global row stride rs) into linear LDS with pre-swizzled SOURCE
__device__ __forceinline__ void stage64(const ushort* __restrict__ g, int rs,
                                        char* lds, int tid) {
    const int r = tid >> 3;
    const int c8 = ((tid & 7) ^ (r & 7)) << 3;
    const int wid = tid >> 6;
    gload_lds16(g + (size_t)r * rs + c8, lds + wid * 1024);
    gload_lds16(g + (size_t)(r + 32) * rs + c8, lds + 4096 + wid * 1024);
}

// stage a 64x128 bf16 tile (rows=d, global row stride 2048) with 16-group source swizzle
__device__ __forceinline__ void stageV128(const ushort* __restrict__ g, char* lds, int tid) {
    const int w = tid >> 6, l = tid & 63;
    const int g16 = l & 15;
#pragma unroll
    for (int j = 0; j < 4; ++j) {
        const int r = w * 16 + j * 4 + (l >> 4);
        gload_lds16(g + (size_t)r * 2048 + ((g16 ^ (r & 15)) << 3), lds + w * 4096 + j * 1024);
    }
}

// ---------- merged fp32->bf16 convert (5 tensors) + RoPE tables, one launch ----------
__global__ void cvt_all(const float* __restrict__ x,  const float* __restrict__ wq,
                        const float* __restrict__ wk, const float* __restrict__ wv,
                        const float* __restrict__ wo, ushort* __restrict__ xb,
                        ushort* __restrict__ wcat, ushort* __restrict__ wob,
                        float* __restrict__ cosT, float* __restrict__ sinT) {
    int i = blockIdx.x * 256 + threadIdx.x;          // 4718592 float4 units + 65536 table
    if (i >= 4718592) {
        int id = i - 4718592;                        // 65536 = 32*2048, layout [32][2048]
        if (id < 65536) {
            int fi = id >> 11, l = id & 2047;
            float freq = __expf(-(float)fi * (9.210340371976184f / 32.0f));
            float ph = (float)l * freq;
            cosT[id] = cosf(ph);
            sinT[id] = sinf(ph);
        }
        return;
    }
    const float* src; ushort* dst; int off;
    if (i < 2097152)      { src = x;  dst = xb;             off = i; }
    else if (i < 3145728) { src = wq; dst = wcat;           off = i - 2097152; }
    else if (i < 3407872) { src = wk; dst = wcat + 4194304; off = i - 3145728; }
    else if (i < 3670016) { src = wv; dst = wcat + 5242880; off = i - 3407872; }
    else                  { src = wo; dst = wob;            off = i - 3670016; }
    float4 v = ((const float4*)src)[off];
    ushort4 o;
    o.x = f2bf(v.x); o.y = f2bf(v.y); o.z = f2bf(v.z); o.w = f2bf(v.w);
    ((ushort4*)dst)[off] = o;
}

// ---------- QKV GEMM: 256x256 BK=64, 8-phase interleaved counted-vmcnt (T3+T4+T5) ----------
// Half-tiles (16KB = 128 rows x 64 cols): h=0,1 -> A halves; h=2,3 -> B halves.
// Iteration i: phases 0-3 compute tile 2i (buf0) while staging tile 2i+1 -> buf1 (1 half/phase);
// phases 4-7 compute 2i+1 (buf1) while staging 2i+2 -> buf0. vmcnt(2) only at switch phases.
__global__ __launch_bounds__(512, 2) void gemmQKV8(const ushort* __restrict__ A,
                                                   const ushort* __restrict__ B,
                                                   ushort* __restrict__ qkv,
                                                   ushort* __restrict__ vt,
                                                   const float* __restrict__ cosT,
                                                   const float* __restrict__ sinT,
                                                   int K, int gx) {
    extern __shared__ __align__(16) ushort sm[];
    ushort* sA = sm;              // 2 bufs x 16384 elems (2 halves x [128][64])
    ushort* sB = sm + 32768;      // 2 bufs x 16384 elems
    const int tid = threadIdx.x, lane = tid & 63, wid = tid >> 6;
    const int wr = wid >> 2, wc = wid & 3;           // 2(M) x 4(N) waves
    const int lr = lane & 15, lg = lane >> 4;
    const int nwg = gridDim.x, bid = blockIdx.x;
    const int swz = (bid & 7) * (nwg >> 3) + (bid >> 3);   // bijective XCD swizzle
    const int m0 = (swz / gx) * 256, n0 = (swz % gx) * 256;
    const int NT = K >> 6;
    const int sr = tid >> 3;                         // 0..63
    const int sc8 = ((tid & 7) ^ (sr & 7)) << 3;     // pre-swizzled source col group
    const ushort* gAt = A + (size_t)(m0 + sr) * K + sc8;
    const ushort* gBt = B + (size_t)(n0 + sr) * K + sc8;

    auto stageH = [&](int t, int h, int buf) {       // one 16KB half-tile, 2 gloads/thread
        const ushort* g = (h < 2 ? gAt + (size_t)(h * 128) * K
                                 : gBt + (size_t)((h - 2) * 128) * K) + t * 64;
        char* ld = (char*)((h < 2) ? (sA + buf * 16384 + h * 8192)
                                   : (sB + buf * 16384 + (h - 2) * 8192)) + wid * 1024;
        gload_lds16(g, ld);                           // rows 0-63 of the half
        gload_lds16(g + (size_t)64 * K, ld + 8192);   // rows 64-127
    };

    f32x4 acc[8][4] = {};
    stageH(0, 0, 0); stageH(0, 1, 0); stageH(0, 2, 0); stageH(0, 3, 0);   // tile 0 -> buf0

    const int NI = NT >> 1;
    for (int i = 0; i < NI; ++i) {
#pragma unroll
        for (int half = 0; half < 2; ++half) {
            const int cur = half;                    // buffer being computed
            const int st = 2 * i + 1 + half;         // tile being staged -> buf cur^1
            const ushort* Ac = sA + cur * 16384 + wr * 8192;        // wave's A half [128][64]
            const ushort* Bc = sB + cur * 16384 + (wc >> 1) * 8192; // wave's B half
            const int brow = (wc & 1) * 64;
            bf16x8 bfr[4][2];
#pragma unroll
            for (int p = 0; p < 4; ++p) {
                if (st < NT) stageH(st, p, cur ^ 1);
                if (p == 0) {                        // buffer switch: verify current tile
                    if (st < NT) asm volatile("s_waitcnt vmcnt(2)" ::: "memory");
                    else         asm volatile("s_waitcnt vmcnt(0)" ::: "memory");
                }
                __builtin_amdgcn_s_barrier();
                if (p == 0) {                        // B-frags once per K-tile
#pragma unroll
                    for (int nf = 0; nf < 4; ++nf)
#pragma unroll
                        for (int kk = 0; kk < 2; ++kk)
                            bfr[nf][kk] = *(const bf16x8*)&Bc[swz8(brow + nf * 16 + lr, kk * 4 + lg)];
                }
                bf16x8 af[2][2];
#pragma unroll
                for (int mi = 0; mi < 2; ++mi)
#pragma unroll
                    for (int kk = 0; kk < 2; ++kk)
                        af[mi][kk] = *(const bf16x8*)&Ac[swz8((p * 2 + mi) * 16 + lr, kk * 4 + lg)];
                __builtin_amdgcn_s_setprio(1);
#pragma unroll
                for (int mi = 0; mi < 2; ++mi)
#pragma unroll
                    for (int nf = 0; nf < 4; ++nf)
#pragma unroll
                        for (int kk = 0; kk < 2; ++kk)
                            acc[p * 2 + mi][nf] = MFMA16(af[mi][kk], bfr[nf][kk], acc[p * 2 + mi][nf]);
                __builtin_amdgcn_s_setprio(0);
                __builtin_amdgcn_s_barrier();
            }
        }
    }

    // epilogue: RoPE on Q (scaled)/K -> qkv; V transpose-scatter -> vt
    const int r0 = m0 + wr * 128 + lg * 4;
    const int c0 = n0 + wc * 64 + lr;
    const int wavecol = n0 + wc * 64;
    if (wavecol >= 2560) {
        const int kh = (wavecol - 2560) >> 6;
        const int b = m0 >> 11;
        const int l0 = r0 & 2047;
#pragma unroll
        for (int ni = 0; ni < 4; ++ni) {
            const int d = lr + ni * 16;
            ushort* vrow = vt + (size_t)((b * 8 + kh) * 64 + d) * 2048 + l0;
#pragma unroll
            for (int mi = 0; mi < 8; ++mi) {
                ushort4 o;
                o.x = f2bf(acc[mi][ni][0]); o.y = f2bf(acc[mi][ni][1]);
                o.z = f2bf(acc[mi][ni][2]); o.w = f2bf(acc[mi][ni][3]);
                *(ushort4*)(vrow + mi * 16) = o;
            }
        }
    } else {
        const float scale = (wavecol < 2048) ? 0.18033688f : 1.0f;
        const int l0 = r0 & 2047;
#pragma unroll
        for (int ni = 0; ni < 2; ++ni) {
            const int i = ni * 16 + lr;
            const float* cp = cosT + i * 2048 + l0;
            const float* sp = sinT + i * 2048 + l0;
#pragma unroll
            for (int mi = 0; mi < 8; ++mi) {
                float4 cv = *(const float4*)(cp + mi * 16);
                float4 sv = *(const float4*)(sp + mi * 16);
#pragma unroll
                for (int r = 0; r < 4; ++r) {
                    float lo = acc[mi][ni][r], hi = acc[mi][ni + 2][r];
                    float c = ((const float*)&cv)[r], s = ((const float*)&sv)[r];
                    size_t row = (size_t)(r0 + mi * 16 + r) * 3072;
                    qkv[row + c0 + ni * 16]      = f2bf((c * lo - s * hi) * scale);
                    qkv[row + c0 + ni * 16 + 32] = f2bf((c * hi + s * lo) * scale);
                }
            }
        }
    }
}

// ---------- o-proj GEMM: 256x128 BK=64, 4-phase interleaved counted-vmcnt, f32 out ----------
// Half-tiles per K-tile: h=0,1 -> A halves (16KB each); h=2 -> B (128x64, 16KB).
// Iteration i: phases 0-1 compute tile 2i (buf0) staging 2i+1 -> buf1 (A halves in p0, B in p1);
// phases 2-3 compute 2i+1 staging 2i+2 -> buf0. vmcnt(4) only at switch phases.
__global__ __launch_bounds__(512, 2) void gemmO8(const ushort* __restrict__ A,
                                                 const ushort* __restrict__ B,
                                                 float* __restrict__ C,
                                                 int N, int K, int gx) {
    extern __shared__ __align__(16) ushort sm[];
    ushort* sA = sm;              // 2 bufs x 16384 elems
    ushort* sB = sm + 32768;      // 2 bufs x 8192 elems
    const int tid = threadIdx.x, lane = tid & 63, wid = tid >> 6;
    const int wr = wid >> 1, wc = wid & 1;           // 4(M) x 2(N) waves
    const int lr = lane & 15, lg = lane >> 4;
    const int nwg = gridDim.x, bid = blockIdx.x;
    const int swz = (bid & 7) * (nwg >> 3) + (bid >> 3);
    const int m0 = (swz / gx) * 256, n0 = (swz % gx) * 128;
    const int NT = K >> 6;
    const int sr = tid >> 3;
    const int sc8 = ((tid & 7) ^ (sr & 7)) << 3;
    const ushort* gAt = A + (size_t)(m0 + sr) * K + sc8;
    const ushort* gBt = B + (size_t)(n0 + sr) * K + sc8;

    auto stageH = [&](int t, int h, int buf) {
        const ushort* g = (h < 2 ? gAt + (size_t)(h * 128) * K : gBt) + t * 64;
        char* ld = (char*)((h < 2) ? (sA + buf * 16384 + h * 8192)
                                   : (sB + buf * 8192)) + wid * 1024;
        gload_lds16(g, ld);
        gload_lds16(g + (size_t)64 * K, ld + 8192);
    };

    f32x4 acc[4][4] = {};
    stageH(0, 0, 0); stageH(0, 1, 0); stageH(0, 2, 0);   // tile 0 -> buf0 (6 loads)

    const int NI = NT >> 1;
    for (int i = 0; i < NI; ++i) {
#pragma unroll
        for (int half = 0; half < 2; ++half) {
            const int cur = half;
            const int st = 2 * i + 1 + half;
            const ushort* Ac = sA + cur * 16384 + (wr >> 1) * 8192;
            const int arow = (wr & 1) * 64;
            const ushort* Bc = sB + cur * 8192;
            const int brow = wc * 64;
            bf16x8 bfr[4][2];
#pragma unroll
            for (int p = 0; p < 2; ++p) {
                if (st < NT) {
                    if (p == 0) { stageH(st, 0, cur ^ 1); stageH(st, 1, cur ^ 1); }
                    else        { stageH(st, 2, cur ^ 1); }
                }
                if (p == 0) {
                    if (st < NT) asm volatile("s_waitcnt vmcnt(4)" ::: "memory");
                    else         asm volatile("s_waitcnt vmcnt(0)" ::: "memory");
                }
                __builtin_amdgcn_s_barrier();
                if (p == 0) {
#pragma unroll
                    for (int nf = 0; nf < 4; ++nf)
#pragma unroll
                        for (int kk = 0; kk < 2; ++kk)
                            bfr[nf][kk] = *(const bf16x8*)&Bc[swz8(brow + nf * 16 + lr, kk * 4 + lg)];
                }
                bf16x8 af[2][2];
#pragma unroll
                for (int mi = 0; mi < 2; ++mi)
#pragma unroll
                    for (int kk = 0; kk < 2; ++kk)
                        af[mi][kk] = *(const bf16x8*)&Ac[swz8(arow + (p * 2 + mi) * 16 + lr, kk * 4 + lg)];
                __builtin_amdgcn_s_setprio(1);
#pragma unroll
                for (int mi = 0; mi < 2; ++mi)
#pragma unroll
                    for (int nf = 0; nf < 4; ++nf)
#pragma unroll
                        for (int kk = 0; kk < 2; ++kk)
                            acc[p * 2 + mi][nf] = MFMA16(af[mi][kk], bfr[nf][kk], acc[p * 2 + mi][nf]);
                __builtin_amdgcn_s_setprio(0);
                __builtin_amdgcn_s_barrier();
            }
        }
    }

    const int r0 = m0 + wr * 64 + lg * 4;
    const int c0 = n0 + wc * 64 + lr;
#pragma unroll
    for (int mi = 0; mi < 4; ++mi)
#pragma unroll
        for (int ni = 0; ni < 4; ++ni)
#pragma unroll
            for (int r = 0; r < 4; ++r)
                C[(size_t)(r0 + mi * 16 + r) * N + c0 + ni * 16] = acc[mi][ni][r];
}

// ---------- flash attention: KVBLK=128, swapped QK^T, static-normalization softmax ----------
__global__ __launch_bounds__(256, 2) void attn_k(const ushort* __restrict__ qkv,
                                                 const ushort* __restrict__ vt,
                                                 ushort* __restrict__ attn) {
    extern __shared__ __align__(16) ushort smem[];
    const int tid = threadIdx.x, lane = tid & 63, wid = tid >> 6;
    const int hl = lane >> 5, lq = lane & 31;
    const int p = blockIdx.x;
    const int head = blockIdx.y, b = blockIdx.z;
    const int kh = head >> 2;

    const ushort* Kg = qkv + (size_t)(b * 2048) * 3072 + 2048 + kh * 64;
    const ushort* Vg = vt + (size_t)((b * 8 + kh) * 64) * 2048;

    for (int ph = 0; ph < 2; ++ph) {
        const int qt = ph ? p : 15 - p;
        const int qb = qt << 7;
        const int qw0 = qb + wid * 32;
        const int q_lane = qw0 + lq;
        const int nt = qt + 1;                    // 128-row kv tiles

        bf16x8 qf[4];
        {
            const ushort* qp = qkv + (size_t)(b * 2048 + qw0 + lq) * 3072 + head * 64 + hl * 8;
#pragma unroll
            for (int j = 0; j < 4; ++j) qf[j] = *(const bf16x8*)(qp + j * 16);
        }
        f32x16 o0 = {}, o1 = {};
        float lsum = 0.f;

        stage64(Kg, 3072, (char*)smem, tid);
        stage64(Kg + (size_t)64 * 3072, 3072, (char*)smem + 8192, tid);
        stageV128(Vg, (char*)(smem + 16384), tid);

        for (int it = 0; it < nt; ++it) {
            const int c = it & 1;
            const int kv0 = it << 7;
            const ushort* Kc = smem + c * 8192;
            const ushort* Vc = smem + 16384 + c * 8192;
            if (it + 1 < nt) {
                const int kv1 = kv0 + 128;
                char* kd = (char*)smem + (c ^ 1) * 16384;
                char* vd = (char*)(smem + 16384) + (c ^ 1) * 16384;
                stage64(Kg + (size_t)kv1 * 3072, 3072, kd, tid);
                stage64(Kg + (size_t)(kv1 + 64) * 3072, 3072, kd + 8192, tid);
                stageV128(Vg + kv1, vd, tid);
                asm volatile("s_waitcnt vmcnt(8)" ::: "memory");
            } else {
                asm volatile("s_waitcnt vmcnt(0)" ::: "memory");
            }
            __builtin_amdgcn_s_barrier();

            f32x16 s0 = {}, s1 = {}, s2 = {}, s3 = {};
            __builtin_amdgcn_s_setprio(1);
#pragma unroll
            for (int j = 0; j < 4; ++j) {
                bf16x8 k0 = *(const bf16x8*)&Kc[swz8(lq, j * 2 + hl)];
                bf16x8 k1 = *(const bf16x8*)&Kc[swz8(32 + lq, j * 2 + hl)];
                bf16x8 k2 = *(const bf16x8*)&Kc[swz8(64 + lq, j * 2 + hl)];
                bf16x8 k3 = *(const bf16x8*)&Kc[swz8(96 + lq, j * 2 + hl)];
                s0 = MFMA32(k0, qf[j], s0);
                s1 = MFMA32(k1, qf[j], s1);
                s2 = MFMA32(k2, qf[j], s2);
                s3 = MFMA32(k3, qf[j], s3);
            }
            __builtin_amdgcn_s_setprio(0);

            if (it == qt) {   // diagonal: only the last iteration masks
#pragma unroll
                for (int i = 0; i < 16; ++i) {
                    int r = (i & 3) + ((i >> 2) << 3) + (hl << 2) + kv0;
                    if (r > q_lane)      s0[i] = -1e30f;
                    if (r + 32 > q_lane) s1[i] = -1e30f;
                    if (r + 64 > q_lane) s2[i] = -1e30f;
                    if (r + 96 > q_lane) s3[i] = -1e30f;
                }
            }
            // P = exp2(S) directly (static normalization; masked -> 0)
#pragma unroll
            for (int i = 0; i < 16; ++i) s0[i] = fexp2(s0[i]);
#pragma unroll
            for (int i = 0; i < 16; ++i) s1[i] = fexp2(s1[i]);
#pragma unroll
            for (int i = 0; i < 16; ++i) s2[i] = fexp2(s2[i]);
#pragma unroll
            for (int i = 0; i < 16; ++i) s3[i] = fexp2(s3[i]);
            f32x16 ts = (s0 + s1) + (s2 + s3);
            float u0 = ts[0] + ts[1], u1 = ts[2] + ts[3], u2 = ts[4] + ts[5], u3 = ts[6] + ts[7];
            float u4 = ts[8] + ts[9], u5 = ts[10] + ts[11], u6 = ts[12] + ts[13], u7 = ts[14] + ts[15];
            float rs = ((u0 + u1) + (u2 + u3)) + ((u4 + u5) + (u6 + u7));
            {
                auto sw = __builtin_amdgcn_permlane32_swap(__float_as_int(rs), __float_as_int(rs), 0, 0);
                rs = __int_as_float(sw[0]) + __int_as_float(sw[1]);
            }
            lsum += rs;

            bf16x8 pf[8];
#define PFB(cc, q0, q1, q2, q3, q4, q5, q6, q7)                                   \
            {                                                                      \
                int pk01 = cvtpk(q0, q1), pk23 = cvtpk(q2, q3);                    \
                int pk45 = cvtpk(q4, q5), pk67 = cvtpk(q6, q7);                    \
                auto sA = __builtin_amdgcn_permlane32_swap(pk01, pk45, 0, 0);      \
                auto sB = __builtin_amdgcn_permlane32_swap(pk23, pk67, 0, 0);      \
                union { int w[4]; bf16x8 v; } u;                                   \
                u.w[0] = sA[0]; u.w[1] = sB[0]; u.w[2] = sA[1]; u.w[3] = sB[1];    \
                pf[cc] = u.v;                                                      \
            }
            PFB(0, s0[0], s0[1], s0[2], s0[3], s0[4], s0[5], s0[6], s0[7])
            PFB(1, s0[8], s0[9], s0[10], s0[11], s0[12], s0[13], s0[14], s0[15])
            PFB(2, s1[0], s1[1], s1[2], s1[3], s1[4], s1[5], s1[6], s1[7])
            PFB(3, s1[8], s1[9], s1[10], s1[11], s1[12], s1[13], s1[14], s1[15])
            PFB(4, s2[0], s2[1], s2[2], s2[3], s2[4], s2[5], s2[6], s2[7])
            PFB(5, s2[8], s2[9], s2[10], s2[11], s2[12], s2[13], s2[14], s2[15])
            PFB(6, s3[0], s3[1], s3[2], s3[3], s3[4], s3[5], s3[6], s3[7])
            PFB(7, s3[8], s3[9], s3[10], s3[11], s3[12], s3[13], s3[14], s3[15])
#undef PFB
            __builtin_amdgcn_s_setprio(1);
#pragma unroll
            for (int cc = 0; cc < 8; ++cc) {
                bf16x8 v0 = *(const bf16x8*)&Vc[swz16(lq, cc * 2 + hl)];
                bf16x8 v1 = *(const bf16x8*)&Vc[swz16(32 + lq, cc * 2 + hl)];
                o0 = MFMA32(v0, pf[cc], o0);
                o1 = MFMA32(v1, pf[cc], o1);
            }
            __builtin_amdgcn_s_setprio(0);
            __builtin_amdgcn_s_barrier();
        }

        __syncthreads();
        ushort* sc = (ushort*)((char*)smem + wid * 4096);
        float inv = 1.0f / lsum;
#pragma unroll
        for (int i = 0; i < 16; i += 2) {
            int d0 = (i & 3) + ((i >> 2) << 3) + (hl << 2);
            int g0 = d0 >> 3, g1 = (d0 + 32) >> 3;
            *(int*)&sc[lq * 64 + ((g0 ^ (lq & 7)) << 3) + (d0 & 7)] = cvtpk(o0[i] * inv, o0[i + 1] * inv);
            *(int*)&sc[lq * 64 + ((g1 ^ (lq & 7)) << 3) + (d0 & 7)] = cvtpk(o1[i] * inv, o1[i + 1] * inv);
        }
        __syncthreads();
        {
            const int q = lane >> 1, db = (lane & 1) << 5;
            const size_t orow = (size_t)(b * 2048 + qb + wid * 32 + q);
#pragma unroll
            for (int j = 0; j < 4; ++j) {
                int g = (db >> 3) + j;
                u16x8 v = *(const u16x8*)&sc[q * 64 + ((g ^ (q & 7)) << 3)];
                *(u16x8*)(attn + orow * 2048 + head * 64 + g * 8) = v;
            }
        }
        __syncthreads();
    }
}

// ---------- launch ----------
extern "C" void kernel_launch(void* const* d_in, const int* in_sizes, int n_in,
                              void* d_out, int out_size, void* d_ws, size_t ws_size,
                              hipStream_t stream) {
    const float* x  = (const float*)d_in[0];
    const float* wq = (const float*)d_in[1];
    const float* wk = (const float*)d_in[2];
    const float* wv = (const float*)d_in[3];
    const float* wo = (const float*)d_in[4];
    float* out = (float*)d_out;
    char* ws = (char*)d_ws;

    ushort* xb   = (ushort*)(ws);                 // 16 MB
    ushort* wcat = (ushort*)(ws + 16777216);      // 12 MB
    ushort* wob  = (ushort*)(ws + 29360128);      // 8 MB
    ushort* qkv  = (ushort*)(ws + 37748736);      // 24 MB
    ushort* vt   = (ushort*)(ws + 62914560);      // 4 MB
    ushort* attn = (ushort*)(ws + 67108864);      // 16 MB
    float*  cosT = (float*)(ws + 83886080);       // [32][2048] f32
    float*  sinT = (float*)(ws + 84148224);

    (void)hipFuncSetAttribute((const void*)gemmQKV8,
                              hipFuncAttributeMaxDynamicSharedMemorySize, 131072);
    (void)hipFuncSetAttribute((const void*)gemmO8,
                              hipFuncAttributeMaxDynamicSharedMemorySize, 98304);
    (void)hipFuncSetAttribute((const void*)attn_k,
                              hipFuncAttributeMaxDynamicSharedMemorySize, 65536);

    // fp32->bf16 conversions + rope tables, one launch
    cvt_all<<<18688, 256, 0, stream>>>(x, wq, wk, wv, wo, xb, wcat, wob, cosT, sinT);
    // QKV projection + fused RoPE + V-transpose (192 blocks, 8-phase, XCD-swizzled)
    gemmQKV8<<<192, 512, 131072, stream>>>(xb, wcat, qkv, vt, cosT, sinT, 2048, 12);
    // flash attention (512 blocks, causal-paired, KVBLK=128, static softmax)
    attn_k<<<dim3(8, 32, 2), 256, 65536, stream>>>(qkv, vt, attn);
    // output projection -> fp32 d_out (256 blocks full chip, 4-phase, XCD-swizzled)
    gemmO8<<<256, 512, 98304, stream>>>(attn, wob, out, 2048, 2048, 16);
}